// Round 1
// baseline (320.299 us; speedup 1.0000x reference)
//
#include <hip/hip_runtime.h>

// GlobalFilter (GFNet): out = irfft2(rfft2(x)·W, ortho) == per-channel 16x16
// circular convolution with k[:,:,c] = inverse-transform of W (Hermitian-
// extended, Im dropped at self-conjugate cols v=0,8). ortho norms cancel.

constexpr int PP = 16;   // patch size
constexpr int NS = 256;  // PP*PP spatial
constexpr int CH = 768;  // channels
constexpr int NB = 128;  // batch

// ---------------- Kernel A: build real conv kernel k[p*16+q][c] -------------
__global__ void gf_build_k(const float* __restrict__ w, float* __restrict__ kbuf) {
    const int pq = blockIdx.x;                              // 0..255
    const int c  = blockIdx.y * blockDim.x + threadIdx.x;   // 0..767
    const int p = pq >> 4, q = pq & 15;

    float ct[16], st[16];
#pragma unroll
    for (int t = 0; t < 16; ++t) {
        const float ang = 6.28318530717958647692f * (float)t * (1.0f / 16.0f);
        ct[t] = cosf(ang);
        st[t] = sinf(ang);
    }

    float acc = 0.0f;
#pragma unroll
    for (int u = 0; u < 16; ++u) {
#pragma unroll
        for (int v = 0; v <= 8; ++v) {
            const float cv = (v == 0 || v == 8) ? 1.0f : 2.0f;
            const int t = (u * p + v * q) & 15;
            const float* wp = w + 2 * ((size_t)((u * 9 + v) * CH) + c);
            acc += cv * (wp[0] * ct[t] - wp[1] * st[t]);
        }
    }
    kbuf[pq * CH + c] = acc * (1.0f / 256.0f);
}

// ---------------- Kernel B: depthwise 16x16 circular conv -------------------
// block = (32 channels, one batch b), 128 threads.
// thread: 4 channels (float4) x 1 n-column x all 16 m rows (64 acc VGPRs).
__global__ __launch_bounds__(128) void gf_conv(const float* __restrict__ x,
                                               const float* __restrict__ kbuf,
                                               float* __restrict__ out) {
    __shared__ __align__(16) float xs[NS][32];
    const int b   = blockIdx.y;
    const int c0  = blockIdx.x * 32;
    const int tid = threadIdx.x;

    // ---- stage x[b, :, c0:c0+32] into LDS (b128 loads/stores) ----
    {
        const int ch4 = (tid & 7) << 2;
        const int sr  = tid >> 3;  // 0..15
        const float* xb = x + (size_t)b * NS * CH + c0;
#pragma unroll
        for (int i = 0; i < 16; ++i) {
            const int s = (i << 4) + sr;
            *(float4*)&xs[s][ch4] = *(const float4*)(xb + (size_t)s * CH + ch4);
        }
    }
    __syncthreads();

    const int ch = (tid & 7) << 2;  // channel within tile (float4 group)
    const int n  = tid >> 3;        // output column 0..15

    float4 acc[16];
#pragma unroll
    for (int m = 0; m < 16; ++m) acc[m] = make_float4(0.f, 0.f, 0.f, 0.f);

    const float* kb = kbuf + c0 + ch;

    // q staggered by n so every lane reads the SAME LDS x-column each step
    // (broadcast -> zero bank conflicts).
#pragma unroll 1
    for (int qq = 0; qq < 16; ++qq) {
        const int q = (qq + n) & 15;
        const int j = (n - q) & 15;  // == (-qq)&15, lane-uniform

        float4 xv[16];
#pragma unroll
        for (int r = 0; r < 16; ++r)
            xv[r] = *(const float4*)&xs[(r << 4) + j][ch];

#pragma unroll
        for (int p = 0; p < 16; ++p) {
            const float4 kv = *(const float4*)(kb + (size_t)(((p << 4) | q)) * CH);
#pragma unroll
            for (int m = 0; m < 16; ++m) {
                const float4 xx = xv[(m - p) & 15];
                acc[m].x = fmaf(kv.x, xx.x, acc[m].x);
                acc[m].y = fmaf(kv.y, xx.y, acc[m].y);
                acc[m].z = fmaf(kv.z, xx.z, acc[m].z);
                acc[m].w = fmaf(kv.w, xx.w, acc[m].w);
            }
        }
    }

    float* ob = out + (size_t)b * NS * CH + c0 + ch;
#pragma unroll
    for (int m = 0; m < 16; ++m)
        *(float4*)(ob + (size_t)((m << 4) + n) * CH) = acc[m];
}

// ---------------------------------------------------------------------------
extern "C" void kernel_launch(void* const* d_in, const int* in_sizes, int n_in,
                              void* d_out, int out_size, void* d_ws, size_t ws_size,
                              hipStream_t stream) {
    const float* x = (const float*)d_in[0];        // [128, 256, 768] fp32
    const float* w = (const float*)d_in[1];        // [16, 9, 768, 2] fp32
    float* out  = (float*)d_out;                   // [128, 256, 768] fp32
    float* kbuf = (float*)d_ws;                    // 256*768 fp32 = 768 KB

    gf_build_k<<<dim3(256, 3), 256, 0, stream>>>(w, kbuf);
    gf_conv<<<dim3(CH / 32, NB), 128, 0, stream>>>(x, kbuf, out);
}